// Round 9
// baseline (52.860 us; speedup 1.0000x reference)
//
#include <hip/hip_runtime.h>

#define D256 256
#define KT 8
#define S_SEQ 1024
#define OUTSEQ 512

typedef __attribute__((ext_vector_type(8))) short bf16x8;
typedef __attribute__((ext_vector_type(8))) unsigned short u16x8;
typedef __attribute__((ext_vector_type(4))) float f32x4;

__device__ inline unsigned short f2bf(float f) {          // RNE fp32->bf16
  unsigned u = __float_as_uint(f);
  return (unsigned short)((u + 0x7fffu + ((u >> 16) & 1u)) >> 16);
}

// ---------------- prep ----------------
// blocks   0..255 : PIt4[j][i] = {P[i][j], 1/p, cb2, 0}, p = i*256+j+2
// blocks 256..511 : LinkTb[t][s] = bf16( s<1024 ? Linker[s][t] : rLinker[s-1024][t] )
// blocks 512..767 : xb  = bf16(x)      (flat convert, 2048 elems/block)
// blocks 768..799 : Mb  = bf16(M)      (flat)
// blocks 800..831 : Wb  = bf16(res_W)  (flat)
__global__ __launch_bounds__(256) void k_prep(const float* __restrict__ x,
                                              const float* __restrict__ M,
                                              const float* __restrict__ resW,
                                              const float* __restrict__ P,
                                              const float* __restrict__ Linker,
                                              const float* __restrict__ rLinker,
                                              float4* __restrict__ PIt4,
                                              unsigned short* __restrict__ LinkTb,
                                              unsigned short* __restrict__ xb,
                                              unsigned short* __restrict__ Mb,
                                              unsigned short* __restrict__ Wb) {
  __shared__ float tl[64][65];
  const int tid = threadIdx.x;
  const int blk = blockIdx.x;
  if (blk < 256) {
    const int j = blk;
    const int t = tid;
    const float p = (float)(t * D256 + j + 2);
    const float ip = 1.0f / p;
    const float cb2 = 2.0f * __builtin_amdgcn_cosf(ip);   // v_cos takes revolutions
    PIt4[j * D256 + t] = make_float4(P[t * D256 + j], ip, cb2, 0.0f);
    return;
  }
  if (blk >= 512) {                     // flat fp32 -> bf16 converts
    const float* src;
    unsigned short* dst;
    size_t base;
    if (blk < 768)      { src = x;    dst = xb; base = (size_t)(blk - 512) * 2048; }
    else if (blk < 800) { src = M;    dst = Mb; base = (size_t)(blk - 768) * 2048; }
    else                { src = resW; dst = Wb; base = (size_t)(blk - 800) * 2048; }
    const size_t off = base + (size_t)tid * 8;
    const float4 v0 = *(const float4*)(src + off);
    const float4 v1 = *(const float4*)(src + off + 4);
    u16x8 o;
    o[0] = f2bf(v0.x); o[1] = f2bf(v0.y); o[2] = f2bf(v0.z); o[3] = f2bf(v0.w);
    o[4] = f2bf(v1.x); o[5] = f2bf(v1.y); o[6] = f2bf(v1.z); o[7] = f2bf(v1.w);
    *(u16x8*)(dst + off) = o;
    return;
  }
  // LinkTb transpose-pack
  const int tb = blk - 256;             // 0..255
  const int st = tb & 31;               // s-tile (64 rows)
  const int tt = tb >> 5;               // t-tile (64 cols)
  const int s0 = st * 64, t0 = tt * 64;
  const float* src = (s0 < 1024) ? (Linker + (size_t)s0 * OUTSEQ)
                                 : (rLinker + (size_t)(s0 - 1024) * OUTSEQ);
  {
    const int sy = tid >> 2, sx = tid & 3;
    #pragma unroll
    for (int c = 0; c < 4; ++c) {
      const int ci = sx + c * 4;
      const float4 v = *(const float4*)&src[sy * OUTSEQ + t0 + ci * 4];
      tl[ci * 4 + 0][sy] = v.x;
      tl[ci * 4 + 1][sy] = v.y;
      tl[ci * 4 + 2][sy] = v.z;
      tl[ci * 4 + 3][sy] = v.w;
    }
  }
  __syncthreads();
  {
    const int ty = tid >> 2, tx = tid & 3;
    u16x8 o0, o1;
    #pragma unroll
    for (int e = 0; e < 8; ++e) o0[e] = f2bf(tl[ty][tx * 16 + e]);
    #pragma unroll
    for (int e = 0; e < 8; ++e) o1[e] = f2bf(tl[ty][tx * 16 + 8 + e]);
    unsigned short* dst = LinkTb + (size_t)(t0 + ty) * 2048 + s0 + tx * 16;
    *(u16x8*)dst = o0;
    *(u16x8*)(dst + 8) = o1;
  }
}

// ---------------- k_Azn: MFMA phase A + LN ----------------
// grid 128 (k-tiles of 16), 256 thr = 4 waves; wave w owns o-cols [w*64, w*64+64)
// Zpre = x@M^T -> LN -> Zb fp32 [k][i];  rfeat = x@resW^T -> Bt[d][2048+k] bf16
__global__ __launch_bounds__(256) void k_Azn(const unsigned short* __restrict__ xb,
                                             const unsigned short* __restrict__ Mb,
                                             const unsigned short* __restrict__ Wb,
                                             const float* __restrict__ gamma,
                                             const float* __restrict__ beta,
                                             float* __restrict__ Zb,
                                             unsigned short* __restrict__ Bt) {
  __shared__ float Zs[16][D256];
  __shared__ float Rs[16][D256];
  __shared__ float mu_s[16], rs_s[16];
  const int k0 = blockIdx.x * 16;
  const int w = threadIdx.x >> 6;
  const int l = threadIdx.x & 63;
  const int m = l & 15, q = l >> 4;

  f32x4 aZ[4] = {}, aR[4] = {};
  const unsigned short* Arow = xb + (size_t)(k0 + m) * D256;
  #pragma unroll
  for (int ks = 0; ks < 8; ++ks) {
    const bf16x8 a = *(const bf16x8*)(Arow + ks * 32 + q * 8);
    #pragma unroll
    for (int cf = 0; cf < 4; ++cf) {
      const int o = w * 64 + cf * 16 + m;
      const bf16x8 bz = *(const bf16x8*)(Mb + (size_t)o * D256 + ks * 32 + q * 8);
      const bf16x8 br = *(const bf16x8*)(Wb + (size_t)o * D256 + ks * 32 + q * 8);
      aZ[cf] = __builtin_amdgcn_mfma_f32_16x16x32_bf16(a, bz, aZ[cf], 0, 0, 0);
      aR[cf] = __builtin_amdgcn_mfma_f32_16x16x32_bf16(a, br, aR[cf], 0, 0, 0);
    }
  }
  #pragma unroll
  for (int cf = 0; cf < 4; ++cf) {
    #pragma unroll
    for (int r = 0; r < 4; ++r) {
      Zs[q * 4 + r][w * 64 + cf * 16 + m] = aZ[cf][r];
      Rs[q * 4 + r][w * 64 + cf * 16 + m] = aR[cf][r];
    }
  }
  __syncthreads();

  // LN stats: wave w reduces rows {w, w+4, w+8, w+12}
  #pragma unroll
  for (int rr = w; rr < 16; rr += 4) {
    float s = 0.f, sq = 0.f;
    #pragma unroll
    for (int p = 0; p < 4; ++p) {
      const float v = Zs[rr][l + 64 * p];
      s += v;
      sq = fmaf(v, v, sq);
    }
    #pragma unroll
    for (int off = 32; off; off >>= 1) {
      s += __shfl_down(s, off);
      sq += __shfl_down(sq, off);
    }
    if (l == 0) {
      const float mu = s * (1.0f / 256.0f);
      const float var = sq * (1.0f / 256.0f) - mu * mu;
      mu_s[rr] = mu;
      rs_s[rr] = rsqrtf(var + 1e-5f);
    }
  }
  __syncthreads();

  // normalize -> Zb fp32; pack rfeat -> Bt bf16 transposed
  {
    const int t = threadIdx.x;
    const float g = gamma[t], be = beta[t];
    u16x8 o0, o1;
    #pragma unroll
    for (int rr = 0; rr < 16; ++rr) {
      Zb[(size_t)(k0 + rr) * D256 + t] = (Zs[rr][t] - mu_s[rr]) * rs_s[rr] * g + be;
      const unsigned short rb = f2bf(Rs[rr][t]);
      if (rr < 8) o0[rr] = rb; else o1[rr - 8] = rb;
    }
    unsigned short* dst = Bt + (size_t)t * 4096 + 2048 + k0;
    *(u16x8*)dst = o0;
    *(u16x8*)(dst + 8) = o1;
  }
}

// ---------------- k_B: cos-einsum, Chebyshev over k-tile ----------------
// grid 512 = (k-tile kt) x (i-half ih); 512 thr = (j-quarter jq) x (i-local il)
// T[k, i] = sum_j Z[k,j]*P[i,j]*cos(2pi*k/p_ij) -> Bt[i][k] bf16
__global__ __launch_bounds__(512) void k_B(const float* __restrict__ Zb,
                                           const float4* __restrict__ PIt4,
                                           unsigned short* __restrict__ Bt) {
  __shared__ float Xs[D256][12];        // [j][k] padded
  __shared__ float red[4][KT][128];     // 16 KB
  const int tid = threadIdx.x;
  const int il = tid & 127;
  const int jq = tid >> 7;              // 0..3, wave-uniform
  const int kt = blockIdx.x >> 1;
  const int ih = blockIdx.x & 1;
  const int k0 = kt * KT;
  const int ib = ih * 128 + il;

  // stage Z tile transposed: [j][k]
  {
    const int i = tid & 255;
    const int h2 = tid >> 8;            // 0..1
    #pragma unroll
    for (int r = 0; r < 4; ++r)
      Xs[i][h2 * 4 + r] = Zb[(size_t)(k0 + h2 * 4 + r) * D256 + i];
  }
  __syncthreads();

  float accT[KT] = {};
  const float kf0 = (float)k0, kf1 = (float)(k0 + 1);
  {
    const float4* pip = PIt4 + ib;
    #pragma unroll 4
    for (int jj = 0; jj < 64; ++jj) {
      const int j = jq * 64 + jj;
      const float4 pi = pip[(size_t)j * D256];       // {P, 1/p, cb2, 0}
      const float4 z0 = *(const float4*)&Xs[j][0];   // broadcast b128
      const float4 z1 = *(const float4*)&Xs[j][4];
      const float r0 = __builtin_amdgcn_fractf(kf0 * pi.y);
      const float r1 = __builtin_amdgcn_fractf(kf1 * pi.y);
      float c0 = __builtin_amdgcn_cosf(r0);
      float c1 = __builtin_amdgcn_cosf(r1);
      accT[0] = fmaf(z0.x * pi.x, c0, accT[0]);
      accT[1] = fmaf(z0.y * pi.x, c1, accT[1]);
      float c2;
      c2 = fmaf(pi.z, c1, -c0); accT[2] = fmaf(z0.z * pi.x, c2, accT[2]); c0 = c1; c1 = c2;
      c2 = fmaf(pi.z, c1, -c0); accT[3] = fmaf(z0.w * pi.x, c2, accT[3]); c0 = c1; c1 = c2;
      c2 = fmaf(pi.z, c1, -c0); accT[4] = fmaf(z1.x * pi.x, c2, accT[4]); c0 = c1; c1 = c2;
      c2 = fmaf(pi.z, c1, -c0); accT[5] = fmaf(z1.y * pi.x, c2, accT[5]); c0 = c1; c1 = c2;
      c2 = fmaf(pi.z, c1, -c0); accT[6] = fmaf(z1.z * pi.x, c2, accT[6]); c0 = c1; c1 = c2;
      c2 = fmaf(pi.z, c1, -c0); accT[7] = fmaf(z1.w * pi.x, c2, accT[7]);
    }
  }
  #pragma unroll
  for (int r = 0; r < KT; ++r) red[jq][r][il] = accT[r];
  __syncthreads();
  if (tid < 128) {
    u16x8 o;
    #pragma unroll
    for (int r = 0; r < KT; ++r)
      o[r] = f2bf(red[0][r][tid] + red[1][r][tid] + red[2][r][tid] + red[3][r][tid]);
    *(u16x8*)(Bt + (size_t)(ih * 128 + tid) * 4096 + k0) = o;
  }
}

// ---------------- k_Cm: bf16 MFMA GEMM, K split 8 ways ----------------
// out[b*512+t][d] = sum_s LinkTb[t][s]*T/rfeat ; grid 512 = kc8 x dt4 x tt8 x b2
__global__ __launch_bounds__(256) void k_Cm(const unsigned short* __restrict__ LinkTb,
                                            const unsigned short* __restrict__ Bt,
                                            float* __restrict__ part) {
  const int bid = blockIdx.x;
  const int kc = bid & 7;
  const int dt = (bid >> 3) & 3;
  const int tt = (bid >> 5) & 7;
  const int b  = bid >> 8;
  const int wv = threadIdx.x >> 6;
  const int l  = threadIdx.x & 63;
  const int wm = wv >> 1, wn = wv & 1;
  const int t0 = tt * 64 + wm * 32;
  const int d0 = dt * 64 + wn * 32;
  const int m  = l & 15;
  const int q  = l >> 4;
  const int sc0 = kc * 128;

  f32x4 acc00 = {}, acc01 = {}, acc10 = {}, acc11 = {};
  const unsigned short* Arow = LinkTb + (size_t)(t0 + m) * 2048;
  const unsigned short* Brow = Bt + (size_t)(d0 + m) * 4096;

  #pragma unroll
  for (int seg = 0; seg < 2; ++seg) {
    const int acol = seg * 1024 + sc0 + q * 8;
    const int bcol = seg * 2048 + b * 1024 + sc0 + q * 8;
    #pragma unroll
    for (int ks = 0; ks < 4; ++ks) {
      const bf16x8 a0 = *(const bf16x8*)(Arow + acol + ks * 32);
      const bf16x8 a1 = *(const bf16x8*)(Arow + 16 * 2048 + acol + ks * 32);
      const bf16x8 b0 = *(const bf16x8*)(Brow + bcol + ks * 32);
      const bf16x8 b1 = *(const bf16x8*)(Brow + 16 * 4096 + bcol + ks * 32);
      acc00 = __builtin_amdgcn_mfma_f32_16x16x32_bf16(a0, b0, acc00, 0, 0, 0);
      acc01 = __builtin_amdgcn_mfma_f32_16x16x32_bf16(a0, b1, acc01, 0, 0, 0);
      acc10 = __builtin_amdgcn_mfma_f32_16x16x32_bf16(a1, b0, acc10, 0, 0, 0);
      acc11 = __builtin_amdgcn_mfma_f32_16x16x32_bf16(a1, b1, acc11, 0, 0, 0);
    }
  }

  float* pb = part + ((size_t)kc << 18) + (size_t)(b * 512 + t0 + q * 4) * D256 + d0 + m;
  #pragma unroll
  for (int reg = 0; reg < 4; ++reg) {
    pb[(0 + reg) * D256 + 0]   = acc00[reg];
    pb[(0 + reg) * D256 + 16]  = acc01[reg];
    pb[(16 + reg) * D256 + 0]  = acc10[reg];
    pb[(16 + reg) * D256 + 16] = acc11[reg];
  }
}

// ---------------- k_Cred: sum the 8 K-chunk partials ----------------
__global__ __launch_bounds__(256) void k_Cred(const float* __restrict__ part,
                                              float* __restrict__ out) {
  const int row = blockIdx.x;   // 0..1023
  const int d   = threadIdx.x;
  float s = 0.f;
  #pragma unroll
  for (int kc = 0; kc < 8; ++kc)
    s += part[((size_t)kc << 18) + row * D256 + d];
  out[row * D256 + d] = s;
}

extern "C" void kernel_launch(void* const* d_in, const int* in_sizes, int n_in,
                              void* d_out, int out_size, void* d_ws, size_t ws_size,
                              hipStream_t stream) {
  const float* x       = (const float*)d_in[0];
  const float* M       = (const float*)d_in[1];
  const float* P       = (const float*)d_in[2];
  const float* Linker  = (const float*)d_in[3];
  const float* gamma   = (const float*)d_in[4];
  const float* beta    = (const float*)d_in[5];
  const float* resW    = (const float*)d_in[6];
  const float* rLinker = (const float*)d_in[7];
  float* out = (float*)d_out;

  char* ws = (char*)d_ws;
  float4*         PIt4   = (float4*)(ws);                           // 1 MB
  unsigned short* LinkTb = (unsigned short*)(ws + 1024 * 1024);     // 2 MB
  unsigned short* Bt     = (unsigned short*)(ws + 3072 * 1024);     // 2 MB
  unsigned short* xb     = (unsigned short*)(ws + 5120 * 1024);     // 1 MB
  unsigned short* Mb     = (unsigned short*)(ws + 6144 * 1024);     // 128 KB
  unsigned short* Wb     = (unsigned short*)(ws + 6272 * 1024);     // 128 KB
  float*          Zb     = (float*)(ws + 6400 * 1024);              // 2 MB
  float*          part   = (float*)(ws + 8448 * 1024);              // 8 MB

  hipLaunchKernelGGL(k_prep, dim3(832),  dim3(256), 0, stream,
                     x, M, resW, P, Linker, rLinker, PIt4, LinkTb, xb, Mb, Wb);
  hipLaunchKernelGGL(k_Azn,  dim3(128),  dim3(256), 0, stream,
                     xb, Mb, Wb, gamma, beta, Zb, Bt);
  hipLaunchKernelGGL(k_B,    dim3(512),  dim3(512), 0, stream, Zb, PIt4, Bt);
  hipLaunchKernelGGL(k_Cm,   dim3(512),  dim3(256), 0, stream, LinkTb, Bt, part);
  hipLaunchKernelGGL(k_Cred, dim3(1024), dim3(256), 0, stream, part, out);
}

// Round 10
// 49.765 us; speedup vs baseline: 1.0622x; 1.0622x over previous
//
#include <hip/hip_runtime.h>

#define D256 256
#define KT 8
#define S_SEQ 1024
#define OUTSEQ 512

typedef __attribute__((ext_vector_type(8))) short bf16x8;
typedef __attribute__((ext_vector_type(8))) unsigned short u16x8;
typedef __attribute__((ext_vector_type(4))) unsigned short u16x4;
typedef __attribute__((ext_vector_type(4))) float f32x4;

__device__ inline unsigned short f2bf(float f) {          // RNE fp32->bf16
  unsigned u = __float_as_uint(f);
  return (unsigned short)((u + 0x7fffu + ((u >> 16) & 1u)) >> 16);
}

// ---------------- prep ----------------
// blocks   0..255 : PIt4[j][i] = {P[i][j], 1/p, cb2, 0}, p = i*256+j+2
// blocks 256..511 : LinkTb[t][s] = bf16( s<1024 ? Linker[s][t] : rLinker[s-1024][t] )
// blocks 512..767 : xb  = bf16(x)      (flat convert, 2048 elems/block)
// blocks 768..799 : Mb  = bf16(M)      (flat)
// blocks 800..831 : Wb  = bf16(res_W)  (flat)
__global__ __launch_bounds__(256) void k_prep(const float* __restrict__ x,
                                              const float* __restrict__ M,
                                              const float* __restrict__ resW,
                                              const float* __restrict__ P,
                                              const float* __restrict__ Linker,
                                              const float* __restrict__ rLinker,
                                              float4* __restrict__ PIt4,
                                              unsigned short* __restrict__ LinkTb,
                                              unsigned short* __restrict__ xb,
                                              unsigned short* __restrict__ Mb,
                                              unsigned short* __restrict__ Wb) {
  __shared__ float tl[64][65];
  const int tid = threadIdx.x;
  const int blk = blockIdx.x;
  if (blk < 256) {
    const int j = blk;
    const int t = tid;
    const float p = (float)(t * D256 + j + 2);
    const float ip = 1.0f / p;
    const float cb2 = 2.0f * __builtin_amdgcn_cosf(ip);   // v_cos takes revolutions
    PIt4[j * D256 + t] = make_float4(P[t * D256 + j], ip, cb2, 0.0f);
    return;
  }
  if (blk >= 512) {                     // flat fp32 -> bf16 converts
    const float* src;
    unsigned short* dst;
    size_t base;
    if (blk < 768)      { src = x;    dst = xb; base = (size_t)(blk - 512) * 2048; }
    else if (blk < 800) { src = M;    dst = Mb; base = (size_t)(blk - 768) * 2048; }
    else                { src = resW; dst = Wb; base = (size_t)(blk - 800) * 2048; }
    const size_t off = base + (size_t)tid * 8;
    const float4 v0 = *(const float4*)(src + off);
    const float4 v1 = *(const float4*)(src + off + 4);
    u16x8 o;
    o[0] = f2bf(v0.x); o[1] = f2bf(v0.y); o[2] = f2bf(v0.z); o[3] = f2bf(v0.w);
    o[4] = f2bf(v1.x); o[5] = f2bf(v1.y); o[6] = f2bf(v1.z); o[7] = f2bf(v1.w);
    *(u16x8*)(dst + off) = o;
    return;
  }
  // LinkTb transpose-pack
  const int tb = blk - 256;             // 0..255
  const int st = tb & 31;               // s-tile (64 rows)
  const int tt = tb >> 5;               // t-tile (64 cols)
  const int s0 = st * 64, t0 = tt * 64;
  const float* src = (s0 < 1024) ? (Linker + (size_t)s0 * OUTSEQ)
                                 : (rLinker + (size_t)(s0 - 1024) * OUTSEQ);
  {
    const int sy = tid >> 2, sx = tid & 3;
    #pragma unroll
    for (int c = 0; c < 4; ++c) {
      const int ci = sx + c * 4;
      const float4 v = *(const float4*)&src[sy * OUTSEQ + t0 + ci * 4];
      tl[ci * 4 + 0][sy] = v.x;
      tl[ci * 4 + 1][sy] = v.y;
      tl[ci * 4 + 2][sy] = v.z;
      tl[ci * 4 + 3][sy] = v.w;
    }
  }
  __syncthreads();
  {
    const int ty = tid >> 2, tx = tid & 3;
    u16x8 o0, o1;
    #pragma unroll
    for (int e = 0; e < 8; ++e) o0[e] = f2bf(tl[ty][tx * 16 + e]);
    #pragma unroll
    for (int e = 0; e < 8; ++e) o1[e] = f2bf(tl[ty][tx * 16 + 8 + e]);
    unsigned short* dst = LinkTb + (size_t)(t0 + ty) * 2048 + s0 + tx * 16;
    *(u16x8*)dst = o0;
    *(u16x8*)(dst + 8) = o1;
  }
}

// ---------------- k_Azn: MFMA phase A + LN ----------------
// grid 128 (k-tiles of 16), 256 thr = 4 waves; wave w owns o-cols [w*64, w*64+64)
// Zpre = x@M^T -> LN -> Zb fp32 [k][i];  rfeat = x@resW^T -> Bt[d][2048+k] bf16
__global__ __launch_bounds__(256) void k_Azn(const unsigned short* __restrict__ xb,
                                             const unsigned short* __restrict__ Mb,
                                             const unsigned short* __restrict__ Wb,
                                             const float* __restrict__ gamma,
                                             const float* __restrict__ beta,
                                             float* __restrict__ Zb,
                                             unsigned short* __restrict__ Bt) {
  __shared__ float Zs[16][D256];
  __shared__ float Rs[16][D256];
  __shared__ float mu_s[16], rs_s[16];
  const int k0 = blockIdx.x * 16;
  const int w = threadIdx.x >> 6;
  const int l = threadIdx.x & 63;
  const int m = l & 15, q = l >> 4;

  f32x4 aZ[4] = {}, aR[4] = {};
  const unsigned short* Arow = xb + (size_t)(k0 + m) * D256;
  #pragma unroll
  for (int ks = 0; ks < 8; ++ks) {
    const bf16x8 a = *(const bf16x8*)(Arow + ks * 32 + q * 8);
    #pragma unroll
    for (int cf = 0; cf < 4; ++cf) {
      const int o = w * 64 + cf * 16 + m;
      const bf16x8 bz = *(const bf16x8*)(Mb + (size_t)o * D256 + ks * 32 + q * 8);
      const bf16x8 br = *(const bf16x8*)(Wb + (size_t)o * D256 + ks * 32 + q * 8);
      aZ[cf] = __builtin_amdgcn_mfma_f32_16x16x32_bf16(a, bz, aZ[cf], 0, 0, 0);
      aR[cf] = __builtin_amdgcn_mfma_f32_16x16x32_bf16(a, br, aR[cf], 0, 0, 0);
    }
  }
  #pragma unroll
  for (int cf = 0; cf < 4; ++cf) {
    #pragma unroll
    for (int r = 0; r < 4; ++r) {
      Zs[q * 4 + r][w * 64 + cf * 16 + m] = aZ[cf][r];
      Rs[q * 4 + r][w * 64 + cf * 16 + m] = aR[cf][r];
    }
  }
  __syncthreads();

  // LN stats: wave w reduces rows {w, w+4, w+8, w+12}
  #pragma unroll
  for (int rr = w; rr < 16; rr += 4) {
    float s = 0.f, sq = 0.f;
    #pragma unroll
    for (int p = 0; p < 4; ++p) {
      const float v = Zs[rr][l + 64 * p];
      s += v;
      sq = fmaf(v, v, sq);
    }
    #pragma unroll
    for (int off = 32; off; off >>= 1) {
      s += __shfl_down(s, off);
      sq += __shfl_down(sq, off);
    }
    if (l == 0) {
      const float mu = s * (1.0f / 256.0f);
      const float var = sq * (1.0f / 256.0f) - mu * mu;
      mu_s[rr] = mu;
      rs_s[rr] = rsqrtf(var + 1e-5f);
    }
  }
  __syncthreads();

  // normalize -> Zb fp32; pack rfeat -> Bt bf16 transposed
  {
    const int t = threadIdx.x;
    const float g = gamma[t], be = beta[t];
    u16x8 o0, o1;
    #pragma unroll
    for (int rr = 0; rr < 16; ++rr) {
      Zb[(size_t)(k0 + rr) * D256 + t] = (Zs[rr][t] - mu_s[rr]) * rs_s[rr] * g + be;
      const unsigned short rb = f2bf(Rs[rr][t]);
      if (rr < 8) o0[rr] = rb; else o1[rr - 8] = rb;
    }
    unsigned short* dst = Bt + (size_t)t * 4096 + 2048 + k0;
    *(u16x8*)dst = o0;
    *(u16x8*)(dst + 8) = o1;
  }
}

// ---------------- k_B: cos-einsum, 16-long Chebyshev chains ----------------
// grid 4096 = (k-tile kt of 16 rows) x (i-group ig of 8); 256 thr = jg(32) x il(8)
// thread: i = ig*8+il, owns j in {jg + 32*jj}, chains over 16 k's.
// In-block jg-reduce in LDS, bf16-pack direct to Bt[i][k].
__global__ __launch_bounds__(256, 6) void k_B(const float* __restrict__ Zb,
                                              const float4* __restrict__ PIt4,
                                              unsigned short* __restrict__ Bt) {
  __shared__ float buf[5120];           // 20 KB: Z[j][20] -> red[jg*132+k*8+il] -> outT
  const int tid = threadIdx.x;
  const int il = tid & 7;
  const int jg = tid >> 3;              // 0..31
  const int ig = blockIdx.x & 31;
  const int kt = blockIdx.x >> 5;
  const int i0 = ig * 8;
  const int k0 = kt * 16;
  const int i  = i0 + il;

  // stage Z tile: buf[j*20 + k] = Zb[k0+k][j]   (coalesced global reads)
  #pragma unroll
  for (int r = 0; r < 16; ++r)
    buf[tid * 20 + r] = Zb[(size_t)(k0 + r) * D256 + tid];
  __syncthreads();

  float acc[16] = {};
  const float kf0 = (float)k0;
  const float4* pip = PIt4 + i;
  #pragma unroll
  for (int jj = 0; jj < 8; ++jj) {
    const int j = jg + 32 * jj;                    // stride-32 j: bank-clean b128 reads
    const float4 pi = pip[(size_t)j * D256];       // {P, 1/p, cb2, 0}
    const float4 z0 = *(const float4*)&buf[j * 20 + 0];   // 8-lane broadcast groups
    const float4 z1 = *(const float4*)&buf[j * 20 + 4];
    const float4 z2 = *(const float4*)&buf[j * 20 + 8];
    const float4 z3 = *(const float4*)&buf[j * 20 + 12];
    const float a = kf0 * pi.y;
    float c0 = __builtin_amdgcn_cosf(__builtin_amdgcn_fractf(a)) * pi.x;       // P folded
    float c1 = __builtin_amdgcn_cosf(__builtin_amdgcn_fractf(a + pi.y)) * pi.x;
    acc[0] = fmaf(z0.x, c0, acc[0]);
    acc[1] = fmaf(z0.y, c1, acc[1]);
    float c2;
    c2 = fmaf(pi.z, c1, -c0); acc[2]  = fmaf(z0.z, c2, acc[2]);  c0 = c1; c1 = c2;
    c2 = fmaf(pi.z, c1, -c0); acc[3]  = fmaf(z0.w, c2, acc[3]);  c0 = c1; c1 = c2;
    c2 = fmaf(pi.z, c1, -c0); acc[4]  = fmaf(z1.x, c2, acc[4]);  c0 = c1; c1 = c2;
    c2 = fmaf(pi.z, c1, -c0); acc[5]  = fmaf(z1.y, c2, acc[5]);  c0 = c1; c1 = c2;
    c2 = fmaf(pi.z, c1, -c0); acc[6]  = fmaf(z1.z, c2, acc[6]);  c0 = c1; c1 = c2;
    c2 = fmaf(pi.z, c1, -c0); acc[7]  = fmaf(z1.w, c2, acc[7]);  c0 = c1; c1 = c2;
    c2 = fmaf(pi.z, c1, -c0); acc[8]  = fmaf(z2.x, c2, acc[8]);  c0 = c1; c1 = c2;
    c2 = fmaf(pi.z, c1, -c0); acc[9]  = fmaf(z2.y, c2, acc[9]);  c0 = c1; c1 = c2;
    c2 = fmaf(pi.z, c1, -c0); acc[10] = fmaf(z2.z, c2, acc[10]); c0 = c1; c1 = c2;
    c2 = fmaf(pi.z, c1, -c0); acc[11] = fmaf(z2.w, c2, acc[11]); c0 = c1; c1 = c2;
    c2 = fmaf(pi.z, c1, -c0); acc[12] = fmaf(z3.x, c2, acc[12]); c0 = c1; c1 = c2;
    c2 = fmaf(pi.z, c1, -c0); acc[13] = fmaf(z3.y, c2, acc[13]); c0 = c1; c1 = c2;
    c2 = fmaf(pi.z, c1, -c0); acc[14] = fmaf(z3.z, c2, acc[14]); c0 = c1; c1 = c2;
    c2 = fmaf(pi.z, c1, -c0); acc[15] = fmaf(z3.w, c2, acc[15]);
  }
  __syncthreads();                      // Z reads done; reuse buf as red

  #pragma unroll
  for (int k = 0; k < 16; ++k)
    buf[jg * 132 + k * 8 + il] = acc[k];   // pad-132: <=2-way write conflicts
  __syncthreads();

  float tv = 0.f;
  if (tid < 128) {                      // tid = k*8 + il
    #pragma unroll
    for (int g = 0; g < 32; ++g) tv += buf[g * 132 + tid];
  }
  __syncthreads();
  if (tid < 128) buf[(tid & 7) * 16 + (tid >> 3)] = tv;   // outT[il][k]
  __syncthreads();
  if (tid < 32) {
    const int iw = tid >> 2;
    const int kq = tid & 3;
    const float4 v = *(const float4*)&buf[iw * 16 + kq * 4];
    u16x4 o;
    o[0] = f2bf(v.x); o[1] = f2bf(v.y); o[2] = f2bf(v.z); o[3] = f2bf(v.w);
    *(u16x4*)(Bt + (size_t)(i0 + iw) * 4096 + k0 + kq * 4) = o;
  }
}

// ---------------- k_Cm: bf16 MFMA GEMM, K split 8 ways ----------------
// out[b*512+t][d] = sum_s LinkTb[t][s]*T/rfeat ; grid 512 = kc8 x dt4 x tt8 x b2
__global__ __launch_bounds__(256) void k_Cm(const unsigned short* __restrict__ LinkTb,
                                            const unsigned short* __restrict__ Bt,
                                            float* __restrict__ part) {
  const int bid = blockIdx.x;
  const int kc = bid & 7;
  const int dt = (bid >> 3) & 3;
  const int tt = (bid >> 5) & 7;
  const int b  = bid >> 8;
  const int wv = threadIdx.x >> 6;
  const int l  = threadIdx.x & 63;
  const int wm = wv >> 1, wn = wv & 1;
  const int t0 = tt * 64 + wm * 32;
  const int d0 = dt * 64 + wn * 32;
  const int m  = l & 15;
  const int q  = l >> 4;
  const int sc0 = kc * 128;

  f32x4 acc00 = {}, acc01 = {}, acc10 = {}, acc11 = {};
  const unsigned short* Arow = LinkTb + (size_t)(t0 + m) * 2048;
  const unsigned short* Brow = Bt + (size_t)(d0 + m) * 4096;

  #pragma unroll
  for (int seg = 0; seg < 2; ++seg) {
    const int acol = seg * 1024 + sc0 + q * 8;
    const int bcol = seg * 2048 + b * 1024 + sc0 + q * 8;
    #pragma unroll
    for (int ks = 0; ks < 4; ++ks) {
      const bf16x8 a0 = *(const bf16x8*)(Arow + acol + ks * 32);
      const bf16x8 a1 = *(const bf16x8*)(Arow + 16 * 2048 + acol + ks * 32);
      const bf16x8 b0 = *(const bf16x8*)(Brow + bcol + ks * 32);
      const bf16x8 b1 = *(const bf16x8*)(Brow + 16 * 4096 + bcol + ks * 32);
      acc00 = __builtin_amdgcn_mfma_f32_16x16x32_bf16(a0, b0, acc00, 0, 0, 0);
      acc01 = __builtin_amdgcn_mfma_f32_16x16x32_bf16(a0, b1, acc01, 0, 0, 0);
      acc10 = __builtin_amdgcn_mfma_f32_16x16x32_bf16(a1, b0, acc10, 0, 0, 0);
      acc11 = __builtin_amdgcn_mfma_f32_16x16x32_bf16(a1, b1, acc11, 0, 0, 0);
    }
  }

  float* pb = part + ((size_t)kc << 18) + (size_t)(b * 512 + t0 + q * 4) * D256 + d0 + m;
  #pragma unroll
  for (int reg = 0; reg < 4; ++reg) {
    pb[(0 + reg) * D256 + 0]   = acc00[reg];
    pb[(0 + reg) * D256 + 16]  = acc01[reg];
    pb[(16 + reg) * D256 + 0]  = acc10[reg];
    pb[(16 + reg) * D256 + 16] = acc11[reg];
  }
}

// ---------------- k_Cred: sum the 8 K-chunk partials ----------------
__global__ __launch_bounds__(256) void k_Cred(const float* __restrict__ part,
                                              float* __restrict__ out) {
  const int row = blockIdx.x;   // 0..1023
  const int d   = threadIdx.x;
  float s = 0.f;
  #pragma unroll
  for (int kc = 0; kc < 8; ++kc)
    s += part[((size_t)kc << 18) + row * D256 + d];
  out[row * D256 + d] = s;
}

extern "C" void kernel_launch(void* const* d_in, const int* in_sizes, int n_in,
                              void* d_out, int out_size, void* d_ws, size_t ws_size,
                              hipStream_t stream) {
  const float* x       = (const float*)d_in[0];
  const float* M       = (const float*)d_in[1];
  const float* P       = (const float*)d_in[2];
  const float* Linker  = (const float*)d_in[3];
  const float* gamma   = (const float*)d_in[4];
  const float* beta    = (const float*)d_in[5];
  const float* resW    = (const float*)d_in[6];
  const float* rLinker = (const float*)d_in[7];
  float* out = (float*)d_out;

  char* ws = (char*)d_ws;
  float4*         PIt4   = (float4*)(ws);                           // 1 MB
  unsigned short* LinkTb = (unsigned short*)(ws + 1024 * 1024);     // 2 MB
  unsigned short* Bt     = (unsigned short*)(ws + 3072 * 1024);     // 2 MB
  unsigned short* xb     = (unsigned short*)(ws + 5120 * 1024);     // 1 MB
  unsigned short* Mb     = (unsigned short*)(ws + 6144 * 1024);     // 128 KB
  unsigned short* Wb     = (unsigned short*)(ws + 6272 * 1024);     // 128 KB
  float*          Zb     = (float*)(ws + 6400 * 1024);              // 2 MB
  float*          part   = (float*)(ws + 8448 * 1024);              // 8 MB

  hipLaunchKernelGGL(k_prep, dim3(832),  dim3(256), 0, stream,
                     x, M, resW, P, Linker, rLinker, PIt4, LinkTb, xb, Mb, Wb);
  hipLaunchKernelGGL(k_Azn,  dim3(128),  dim3(256), 0, stream,
                     xb, Mb, Wb, gamma, beta, Zb, Bt);
  hipLaunchKernelGGL(k_B,    dim3(4096), dim3(256), 0, stream, Zb, PIt4, Bt);
  hipLaunchKernelGGL(k_Cm,   dim3(512),  dim3(256), 0, stream, LinkTb, Bt, part);
  hipLaunchKernelGGL(k_Cred, dim3(1024), dim3(256), 0, stream, part, out);
}